// Round 6
// baseline (14992.587 us; speedup 1.0000x reference)
//
#include <hip/hip_runtime.h>
#include <hip/hip_fp16.h>

#define B_ 256
#define S_ 512
#define F_ 64
#define H_ 1024
#define O_ 24
#define G_ 4096  // 4*H
#define NT_ 64   // ht' tile count (16-col tiles)
#define TPL_ 8   // timesteps per launch
#define RING_ 9  // h ring depth (>= TPL_+1: no address reuse within a launch)

typedef _Float16 half_t;
typedef _Float16 h8 __attribute__((ext_vector_type(8)));
typedef float f4 __attribute__((ext_vector_type(4)));

// ---- workspace layout (bytes) ----
#define OFF_H1 ((size_t)0)                                   // RING_*B*H halfs
#define OFF_H2 (OFF_H1 + (size_t)RING_*B_*H_*2)
#define OFF_C1 (OFF_H2 + (size_t)RING_*B_*H_*2)              // B*H f32
#define OFF_C2 (OFF_C1 + (size_t)B_*H_*4)
#define OFF_OP (OFF_C2 + (size_t)B_*H_*4)                    // out_part [64][B][O] f32
#define OFF_CNT (OFF_OP + (size_t)NT_*B_*O_*4)               // barrier counter
#define ZBYTES (OFF_CNT + 64)
#define OFF_BIAS0 (ZBYTES)
#define OFF_BIAS1 (OFF_BIAS0 + (size_t)G_*4)
#define OFF_XH    (OFF_BIAS1 + (size_t)G_*4)                 // B*S*F halfs
#define OFF_WIH0  (OFF_XH + (size_t)B_*S_*F_*2)              // packed, G*F halfs
#define OFF_WHH0  (OFF_WIH0 + (size_t)G_*F_*2)               // packed, G*H halfs
#define OFF_WIH1  (OFF_WHH0 + (size_t)G_*H_*2)
#define OFF_WHH1  (OFF_WIH1 + (size_t)G_*H_*2)
#define WS_NEEDED (OFF_WHH1 + (size_t)G_*H_*2)               // ~55 MiB

__global__ void k_bias(const float* __restrict__ bi0, const float* __restrict__ bh0,
                       const float* __restrict__ bi1, const float* __restrict__ bh1,
                       float* __restrict__ bias0, float* __restrict__ bias1) {
    int i = blockIdx.x * blockDim.x + threadIdx.x;
    if (i < G_) { bias0[i] = bi0[i] + bh0[i]; bias1[i] = bi1[i] + bh1[i]; }
}

__global__ void k_cvt(const float* __restrict__ src, half_t* __restrict__ dst, int n) {
    int i = blockIdx.x * blockDim.x + threadIdx.x;
    int stride = gridDim.x * blockDim.x;
    for (; i < n; i += stride) dst[i] = (half_t)src[i];
}

// Pack W [4H, NC*64] f32 -> fp16 MFMA-fragment order:
// dst h8 index i = (((g*32+ht)*NC + ck)*4 + j)*64 + lane, j = colhalf*2 + kshalf
__global__ void k_pack(const float* __restrict__ src, half_t* __restrict__ dst, int NC) {
    int i = blockIdx.x * blockDim.x + threadIdx.x;
    int total = 32768 * NC;          // 4*32*NC*4*64
    if (i >= total) return;
    int lane = i & 63;
    int j    = (i >> 6) & 3;
    int ck   = (i >> 8) % NC;
    int gh   = i / (256 * NC);       // g*32+ht, 0..127
    int srow = (gh >> 5) * H_ + (gh & 31) * 32 + (j >> 1) * 16 + (lane & 15);
    int scol = ck * 64 + (j & 1) * 32 + (lane >> 4) * 8;
    const float* s = src + (size_t)srow * (NC * 64) + scol;
    h8 v;
    #pragma unroll
    for (int e = 0; e < 8; ++e) v[e] = (half_t)s[e];
    *(h8*)&dst[(size_t)i * 8] = v;
}

// ---------------------------------------------------------------------------
// R6: launch-merge pass. R1/R2/R4/R5 evidence: phase time is pinned ~19us
// under every internal restructure while bottom-up in-kernel cost is ~5-6us
// -> bound by per-dispatch overhead x513 + cold-L2-per-launch. Merge 8
// phases/launch (65 dispatches) with an L2-PRESERVING grid barrier:
//  * barrier = RELAXED-only device atomics (no acquire/release -> no
//    buffer_inv; the prior session's 5x-worse persistent kernel died on
//    acquire-poll L2 invalidation, 11GB refetch).
//  * h exchange: writers use relaxed agent-scope ATOMIC stores (write-through
//    to LLC past the non-coherent XCD L2); readers use NORMAL cached loads,
//    safe because of a depth-9 ring (an h address is never re-read within a
//    launch -> no stale line can exist; launch boundaries handle cross-launch).
//  * W/x/fcW stay L2-warm across the 8 internal phases (W from LLC once per
//    8 phases, not every phase).
//  * c-state in registers across phases (global c RMW /8); FC partials in
//    registers (out_part RMW /8).
//  * deadlock-proof WITHOUT cooperative launch: __launch_bounds__(512,4)
//    (VGPR<=128) + LDS 72KB -> 2 blocks/CU always possible -> all 256 blocks
//    resident under any placement.
// Inner K-loop = R4-proven body, untouched.
// ---------------------------------------------------------------------------

__device__ __forceinline__ void gbar(unsigned int* cnt, unsigned int target, int thr) {
    __syncthreads();                 // drains vmcnt: all this block's h-stores at LLC
    if (thr == 0) {
        asm volatile("" ::: "memory");
        __hip_atomic_fetch_add(cnt, 1u, __ATOMIC_RELAXED, __HIP_MEMORY_SCOPE_AGENT);
        while (__hip_atomic_load(cnt, __ATOMIC_RELAXED, __HIP_MEMORY_SCOPE_AGENT) < target)
            __builtin_amdgcn_s_sleep(4);
        asm volatile("" ::: "memory");
    }
    __syncthreads();
}

__device__ __forceinline__ void run_part(
    const int thr, const int bt, const int htp,
    const int cx, const int nchunks,
    const half_t* __restrict__ xb, const int ldx,
    const half_t* __restrict__ hp,
    const half_t* __restrict__ Wih, const half_t* __restrict__ Whh,
    const float bv,
    float& cpe, float& cpo, half_t* __restrict__ hn_out,
    const float* __restrict__ fcWt,
    float& fp0, float& fp1, float& fp2,
    half_t* A_s, float* gate_s, float* h_s, float* fcw_s,
    const bool do_fc)
{
    const int wave = thr >> 6, lane = thr & 63;
    const int gate = wave >> 1, mh = wave & 1;
    const int quad = lane >> 4, l15 = lane & 15;
    const int ar = thr >> 3;             // A staging row 0..63
    const int ak = (thr & 7) * 8;        // A staging k-offset (halfs)
    const int ghW = gate * 32 + (htp >> 1);
    const int jo  = (htp & 1) * 2;       // fragment col-half select

    f4 acc0 = (f4){bv, bv, bv, bv};      // rows mh*32 + 0..15
    f4 acc1 = acc0;                      // rows mh*32 + 16..31

    auto loadA = [&](int ck) -> f4 {
        const half_t* Ab; int lda, k0;
        if (ck < cx) { Ab = xb; lda = ldx; k0 = ck * 64; }
        else         { Ab = hp; lda = H_;  k0 = (ck - cx) * 64; }
        return *(const f4*)&Ab[(size_t)(bt * 64 + ar) * lda + k0 + ak];
    };
    auto fetchW = [&](int ck, h8& r0, h8& r1) {
        const half_t* Wb; int ckk, NC;
        if (ck < cx) { Wb = Wih; ckk = ck;      NC = cx; }
        else         { Wb = Whh; ckk = ck - cx; NC = 16; }
        const half_t* base = Wb + ((size_t)(((ghW * NC) + ckk) * 4 + jo) * 64 + lane) * 8;
        r0 = *(const h8*)(base + 0 * 512);
        r1 = *(const h8*)(base + 1 * 512);
    };

    // ---- prologue: window 0 A loads + W chunks 0..2 ----
    h8 W0a,W0b, W1a,W1b, W2a,W2b, W3a,W3b;
    f4 p0, p1, p2, p3;
    f4 a0_ = loadA(0), a1_ = loadA(1), a2_ = loadA(2), a3_ = loadA(3);
    p0 = loadA(4); p1 = loadA(5); p2 = loadA(6); p3 = loadA(7);
    fetchW(0, W0a, W0b);
    fetchW(1, W1a, W1b);
    fetchW(2, W2a, W2b);

    // fcW slice prefetch (l1 only): const + HBM-cold, hidden under K-loop
    float fpre = 0.f;
    if (do_fc && thr < 384)
        fpre = fcWt[(size_t)(thr >> 4) * (S_ * H_) + htp * 16 + (thr & 15)];

    *(f4*)&A_s[0 * 4608 + ar * 72 + ak] = a0_;
    *(f4*)&A_s[1 * 4608 + ar * 72 + ak] = a1_;
    *(f4*)&A_s[2 * 4608 + ar * 72 + ak] = a2_;
    *(f4*)&A_s[3 * 4608 + ar * 72 + ak] = a3_;
    __syncthreads();   // window 0 visible

    for (int s = 0; s < nchunks; s += 4) {
        const int rem = nchunks - s;
        const int ns = rem < 4 ? rem : 4;                 // block-uniform
        int ns2 = rem - 4; if (ns2 < 0) ns2 = 0; if (ns2 > 4) ns2 = 4;
        const int bufo = ((s >> 2) & 1) * 18432;          // read buffer (halfs)
        const int obuf = 18432 - bufo;                    // write buffer

        // issue NEXT window's A loads (latency hides under compute)
        if (ns2 > 0) p0 = loadA(s + 4);
        if (ns2 > 1) p1 = loadA(s + 5);
        if (ns2 > 2) p2 = loadA(s + 6);
        if (ns2 > 3) p3 = loadA(s + 7);

        // compute ns chunks; W pipeline 3 ahead (4 sets, chunk c -> set c&3)
        #define STEP(i, C0,C1, N0,N1)                                                          \
        if (i < ns) {                                                                          \
            if (s + i + 3 < nchunks) fetchW(s + i + 3, N0, N1);                                \
            h8 a0 = *(const h8*)&A_s[bufo + i * 4608 + (mh * 32 + l15) * 72 + quad * 8];       \
            h8 a1 = *(const h8*)&A_s[bufo + i * 4608 + (mh * 32 + 16 + l15) * 72 + quad * 8];  \
            h8 a2 = *(const h8*)&A_s[bufo + i * 4608 + (mh * 32 + l15) * 72 + 32 + quad * 8];  \
            h8 a3 = *(const h8*)&A_s[bufo + i * 4608 + (mh * 32 + 16 + l15) * 72 + 32 + quad * 8]; \
            acc0 = __builtin_amdgcn_mfma_f32_16x16x32_f16(a0, C0, acc0, 0, 0, 0);              \
            acc1 = __builtin_amdgcn_mfma_f32_16x16x32_f16(a1, C0, acc1, 0, 0, 0);              \
            acc0 = __builtin_amdgcn_mfma_f32_16x16x32_f16(a2, C1, acc0, 0, 0, 0);              \
            acc1 = __builtin_amdgcn_mfma_f32_16x16x32_f16(a3, C1, acc1, 0, 0, 0);              \
        }
        STEP(0, W0a,W0b, W3a,W3b)
        STEP(1, W1a,W1b, W0a,W0b)
        STEP(2, W2a,W2b, W1a,W1b)
        STEP(3, W3a,W3b, W2a,W2b)
        #undef STEP

        // store next window into the other buffer; ONE barrier per window
        if (ns2 > 0) {
            /*always*/       *(f4*)&A_s[obuf + 0 * 4608 + ar * 72 + ak] = p0;
            if (ns2 > 1)     *(f4*)&A_s[obuf + 1 * 4608 + ar * 72 + ak] = p1;
            if (ns2 > 2)     *(f4*)&A_s[obuf + 2 * 4608 + ar * 72 + ak] = p2;
            if (ns2 > 3)     *(f4*)&A_s[obuf + 3 * 4608 + ar * 72 + ak] = p3;
            __syncthreads();
        }
    }
    __syncthreads();   // all waves done with A windows before LDS reuse

    // scatter gates (C/D layout: col=lane&15, row=quad*4+reg)
    #pragma unroll
    for (int r = 0; r < 4; ++r) {
        gate_s[gate * (64 * 17) + (mh * 32 + quad * 4 + r) * 17 + l15]      = acc0[r];
        gate_s[gate * (64 * 17) + (mh * 32 + 16 + quad * 4 + r) * 17 + l15] = acc1[r];
    }
    __syncthreads();

    // cell update: 64 rows x 16 cols; thread -> (row=thr>>3, col pair 2c,2c+1)
    // c lives in registers (cpe/cpo) across phases; h written via relaxed
    // agent-scope atomic store (write-through past non-coherent XCD L2).
    {
        const int erow = thr >> 3, ecp = thr & 7;
        const int c0 = 2 * ecp;
        float ge = gate_s[0 * (64 * 17) + erow * 17 + c0];
        float go_ = gate_s[0 * (64 * 17) + erow * 17 + c0 + 1];
        float fe = gate_s[1 * (64 * 17) + erow * 17 + c0];
        float fo = gate_s[1 * (64 * 17) + erow * 17 + c0 + 1];
        float gge = gate_s[2 * (64 * 17) + erow * 17 + c0];
        float ggo = gate_s[2 * (64 * 17) + erow * 17 + c0 + 1];
        float oe = gate_s[3 * (64 * 17) + erow * 17 + c0];
        float oo = gate_s[3 * (64 * 17) + erow * 17 + c0 + 1];
        float sie = 1.f / (1.f + __expf(-ge)),  sio = 1.f / (1.f + __expf(-go_));
        float sfe = 1.f / (1.f + __expf(-fe)),  sfo = 1.f / (1.f + __expf(-fo));
        float soe = 1.f / (1.f + __expf(-oe)),  soo = 1.f / (1.f + __expf(-oo));
        float tge = tanhf(gge), tgo = tanhf(ggo);
        float cne = sfe * cpe + sie * tge;
        float cno = sfo * cpo + sio * tgo;
        cpe = cne; cpo = cno;
        float hne = soe * tanhf(cne);
        float hno = soo * tanhf(cno);
        union { half_t h[2]; unsigned int u; } cv;
        cv.h[0] = (half_t)hne; cv.h[1] = (half_t)hno;
        size_t hidx = (size_t)(bt * 64 + erow) * H_ + htp * 16 + c0;
        __hip_atomic_store((unsigned int*)&hn_out[hidx], cv.u,
                           __ATOMIC_RELAXED, __HIP_MEMORY_SCOPE_AGENT);
        if (do_fc) { h_s[erow * 17 + c0] = hne; h_s[erow * 17 + c0 + 1] = hno; }
    }

    if (do_fc) {
        if (thr < 384) fcw_s[thr] = fpre;   // [24][16] staged from prefetch
        __syncthreads();
        #pragma unroll
        for (int q = 0; q < 3; ++q) {
            int p = thr + q * 512;           // 0..1535 = 64b x 24o
            int o = p >> 6, bb = p & 63;
            float s2 = 0.f;
            #pragma unroll
            for (int j = 0; j < 16; ++j)
                s2 += h_s[bb * 17 + j] * fcw_s[o * 16 + j];
            if (q == 0) fp0 += s2; else if (q == 1) fp1 += s2; else fp2 += s2;
        }
    }
    __syncthreads();   // guard LDS reuse by the next part
}

__global__ __launch_bounds__(512, 4)
void k_mphase(int tbeg, int tcnt, unsigned int* __restrict__ cnt,
              const half_t* __restrict__ x_h,
              const half_t* __restrict__ Wih0, const half_t* __restrict__ Whh0,
              const float* __restrict__ bias0, float* __restrict__ c1g, half_t* __restrict__ h1r,
              const half_t* __restrict__ Wih1, const half_t* __restrict__ Whh1,
              const float* __restrict__ bias1, float* __restrict__ c2g, half_t* __restrict__ h2r,
              const float* __restrict__ fcW, float* __restrict__ out_part)
{
    // double-buffered A: 2 x [4][64*72] halfs = 73728 B; epilogue LDS unioned
    __shared__ __align__(16) char smraw[73728];
    half_t* A_s    = (half_t*)smraw;
    float*  gate_s = (float*)smraw;                  // [4][64*17] = 17408 B
    float*  h_s    = (float*)(smraw + 17408);        // [64*17]    =  4352 B
    float*  fcw_s  = (float*)(smraw + 21760);        // [24*16]    =  1536 B

    const int n   = blockIdx.x;
    const int htp = (n & 7) + 8 * ((n >> 3) & 7);    // htp % 8 == n % 8 (XCD-resident W)
    const int bt  = (n >> 6) & 3;
    const int thr = threadIdx.x;
    const int wave = thr >> 6, lane = thr & 63;
    const int gate = wave >> 1, l15 = lane & 15;

    // persistent per-launch state (block owns its (b,h) slice exclusively)
    const int erow = thr >> 3, ecp = thr & 7;
    const size_t cb = (size_t)(bt * 64 + erow) * H_ + htp * 16 + 2 * ecp;
    float c1e = c1g[cb], c1o = c1g[cb + 1];          // cross-launch via L2 flush
    float c2e = c2g[cb], c2o = c2g[cb + 1];
    float fp0 = 0.f, fp1 = 0.f, fp2 = 0.f;
    const float bv0 = bias0[gate * H_ + htp * 16 + l15];
    const float bv1 = bias1[gate * H_ + htp * 16 + l15];

    for (int p = 0; p < tcnt; ++p) {
        const int t = tbeg + p;
        if (t < S_) {       // layer-0: h1(t) from x(t), h1(t-1)
            run_part(thr, bt, htp, /*cx=*/1, /*nchunks=*/17,
                     x_h + (size_t)t * F_, S_ * F_,
                     h1r + (size_t)((t + RING_ - 1) % RING_) * B_ * H_,
                     Wih0, Whh0, bv0, c1e, c1o,
                     h1r + (size_t)(t % RING_) * B_ * H_,
                     nullptr, fp0, fp1, fp2,
                     A_s, gate_s, h_s, fcw_s, false);
        }
        if (t > 0) {        // layer-1: h2(t-1) from h1(t-1), h2(t-2); + FC
            const int tt = t - 1;
            run_part(thr, bt, htp, /*cx=*/16, /*nchunks=*/32,
                     h1r + (size_t)(tt % RING_) * B_ * H_, H_,
                     h2r + (size_t)((tt + RING_ - 1) % RING_) * B_ * H_,
                     Wih1, Whh1, bv1, c2e, c2o,
                     h2r + (size_t)(tt % RING_) * B_ * H_,
                     fcW + (size_t)tt * H_, fp0, fp1, fp2,
                     A_s, gate_s, h_s, fcw_s, true);
        }
        gbar(cnt, 256u * (unsigned)(t + 1), thr);
    }

    // write back persistent state (normal stores; launch release flushes L2)
    c1g[cb] = c1e; c1g[cb + 1] = c1o;
    c2g[cb] = c2e; c2g[cb + 1] = c2o;
    #pragma unroll
    for (int q = 0; q < 3; ++q) {
        int p = thr + q * 512;
        int o = p >> 6, bb = p & 63;
        size_t oi = (size_t)htp * (B_ * O_) + (bt * 64 + bb) * O_ + o;
        out_part[oi] += (q == 0 ? fp0 : (q == 1 ? fp1 : fp2));
    }
}

__global__ void k_final(const float* __restrict__ out_part, const float* __restrict__ fcb,
                        float* __restrict__ out) {
    int i = blockIdx.x * blockDim.x + threadIdx.x;
    if (i >= B_ * O_) return;
    int o = i % O_;
    float s = fcb[o];
    for (int tl = 0; tl < NT_; ++tl) s += out_part[(size_t)tl * (B_ * O_) + i];
    out[i] = s;
}

extern "C" void kernel_launch(void* const* d_in, const int* in_sizes, int n_in,
                              void* d_out, int out_size, void* d_ws, size_t ws_size,
                              hipStream_t stream) {
    const float* x    = (const float*)d_in[0];
    const float* Wih0 = (const float*)d_in[1];
    const float* Whh0 = (const float*)d_in[2];
    const float* bih0 = (const float*)d_in[3];
    const float* bhh0 = (const float*)d_in[4];
    const float* Wih1 = (const float*)d_in[5];
    const float* Whh1 = (const float*)d_in[6];
    const float* bih1 = (const float*)d_in[7];
    const float* bhh1 = (const float*)d_in[8];
    const float* fcW  = (const float*)d_in[9];
    const float* fcb  = (const float*)d_in[10];

    char* ws = (char*)d_ws;
    half_t* h1r    = (half_t*)(ws + OFF_H1);
    half_t* h2r    = (half_t*)(ws + OFF_H2);
    float*  c1     = (float*)(ws + OFF_C1);
    float*  c2     = (float*)(ws + OFF_C2);
    float*  opart  = (float*)(ws + OFF_OP);
    unsigned int* cnt = (unsigned int*)(ws + OFF_CNT);
    float*  bias0  = (float*)(ws + OFF_BIAS0);
    float*  bias1  = (float*)(ws + OFF_BIAS1);
    half_t* x_h    = (half_t*)(ws + OFF_XH);
    half_t* wih0_p = (half_t*)(ws + OFF_WIH0);
    half_t* whh0_p = (half_t*)(ws + OFF_WHH0);
    half_t* wih1_p = (half_t*)(ws + OFF_WIH1);
    half_t* whh1_p = (half_t*)(ws + OFF_WHH1);

    // zero h rings + c states + FC partials + barrier counter
    hipMemsetAsync(d_ws, 0, ZBYTES, stream);

    k_bias<<<dim3((G_ + 255) / 256), dim3(256), 0, stream>>>(bih0, bhh0, bih1, bhh1, bias0, bias1);
    k_cvt<<<dim3(2048), dim3(256), 0, stream>>>(x, x_h, B_ * S_ * F_);
    k_pack<<<dim3(128),  dim3(256), 0, stream>>>(Wih0, wih0_p, 1);
    k_pack<<<dim3(2048), dim3(256), 0, stream>>>(Whh0, whh0_p, 16);
    k_pack<<<dim3(2048), dim3(256), 0, stream>>>(Wih1, wih1_p, 16);
    k_pack<<<dim3(2048), dim3(256), 0, stream>>>(Whh1, whh1_p, 16);

    for (int tb = 0; tb <= S_; tb += TPL_) {
        int tc = S_ + 1 - tb; if (tc > TPL_) tc = TPL_;
        k_mphase<<<dim3(256), dim3(512), 0, stream>>>(tb, tc, cnt, x_h,
                                                      wih0_p, whh0_p, bias0, c1, h1r,
                                                      wih1_p, whh1_p, bias1, c2, h2r,
                                                      fcW, opart);
    }
    k_final<<<dim3((B_ * O_ + 255) / 256), dim3(256), 0, stream>>>(opart, fcb, (float*)d_out);
}

// Round 7
// 14271.889 us; speedup vs baseline: 1.0505x; 1.0505x over previous
//
#include <hip/hip_runtime.h>
#include <hip/hip_fp16.h>

#define B_ 256
#define S_ 512
#define F_ 64
#define H_ 1024
#define O_ 24
#define G_ 4096  // 4*H
#define NT_ 64   // ht' tile count (16-col tiles)
#define TPL_ 8   // timesteps per launch
#define RING_ 9  // h ring depth (>= TPL_+1: no address reuse within a launch)

typedef _Float16 half_t;
typedef _Float16 h8 __attribute__((ext_vector_type(8)));
typedef float f4 __attribute__((ext_vector_type(4)));

// ---- workspace layout (bytes) ----
#define OFF_H1 ((size_t)0)                                   // RING_*B*H halfs
#define OFF_H2 (OFF_H1 + (size_t)RING_*B_*H_*2)
#define OFF_C1 (OFF_H2 + (size_t)RING_*B_*H_*2)              // B*H f32
#define OFF_C2 (OFF_C1 + (size_t)B_*H_*4)
#define OFF_OP (OFF_C2 + (size_t)B_*H_*4)                    // out_part [64][B][O] f32
#define OFF_CNT (OFF_OP + (size_t)NT_*B_*O_*4)               // barrier counter
#define ZBYTES (OFF_CNT + 64)
#define OFF_BIAS0 (ZBYTES)
#define OFF_BIAS1 (OFF_BIAS0 + (size_t)G_*4)
#define OFF_XH    (OFF_BIAS1 + (size_t)G_*4)                 // B*S*F halfs
#define OFF_WIH0  (OFF_XH + (size_t)B_*S_*F_*2)              // packed, G*F halfs
#define OFF_WHH0  (OFF_WIH0 + (size_t)G_*F_*2)               // packed, G*H halfs
#define OFF_WIH1  (OFF_WHH0 + (size_t)G_*H_*2)
#define OFF_WHH1  (OFF_WIH1 + (size_t)G_*H_*2)
#define WS_NEEDED (OFF_WHH1 + (size_t)G_*H_*2)               // ~55 MiB

__global__ void k_bias(const float* __restrict__ bi0, const float* __restrict__ bh0,
                       const float* __restrict__ bi1, const float* __restrict__ bh1,
                       float* __restrict__ bias0, float* __restrict__ bias1) {
    int i = blockIdx.x * blockDim.x + threadIdx.x;
    if (i < G_) { bias0[i] = bi0[i] + bh0[i]; bias1[i] = bi1[i] + bh1[i]; }
}

__global__ void k_cvt(const float* __restrict__ src, half_t* __restrict__ dst, int n) {
    int i = blockIdx.x * blockDim.x + threadIdx.x;
    int stride = gridDim.x * blockDim.x;
    for (; i < n; i += stride) dst[i] = (half_t)src[i];
}

// Pack W [4H, NC*64] f32 -> fp16 MFMA-fragment order:
// dst h8 index i = (((g*32+ht)*NC + ck)*4 + j)*64 + lane, j = colhalf*2 + kshalf
__global__ void k_pack(const float* __restrict__ src, half_t* __restrict__ dst, int NC) {
    int i = blockIdx.x * blockDim.x + threadIdx.x;
    int total = 32768 * NC;          // 4*32*NC*4*64
    if (i >= total) return;
    int lane = i & 63;
    int j    = (i >> 6) & 3;
    int ck   = (i >> 8) % NC;
    int gh   = i / (256 * NC);       // g*32+ht, 0..127
    int srow = (gh >> 5) * H_ + (gh & 31) * 32 + (j >> 1) * 16 + (lane & 15);
    int scol = ck * 64 + (j & 1) * 32 + (lane >> 4) * 8;
    const float* s = src + (size_t)srow * (NC * 64) + scol;
    h8 v;
    #pragma unroll
    for (int e = 0; e < 8; ++e) v[e] = (half_t)s[e];
    *(h8*)&dst[(size_t)i * 8] = v;
}

// ---------------------------------------------------------------------------
// R7: fix the two defects R6's counters exposed (245us/dispatch, VGPR=64,
// FETCH 333MB/dispatch = 42MB/phase L2-miss @1.6TB/s, MfmaUtil 8.5%):
//  1. __launch_bounds__(512,4) starved the kernel to 64 VGPR -> the W/A
//     register pipelines were dissolved (loads rematerialized at use ->
//     serial latency). Now (512,2): up to 256 VGPR. grid=256 on 256 CUs,
//     8 waves/block -> every block resident under any placement (barrier-safe).
//  2. L2 thrash: unique W (24.5MB, 3.1MB/XCD under n%8 map) was evicted every
//     phase by the h/x/c/fcW STREAMS -> W re-missed to LLC/HBM each phase.
//     Fix: non-temporal loads/stores on all streaming accesses (A loads,
//     fcW prefetch, c load/store, out_part RMW). W + bias are now the only
//     L2-allocating data -> W stays L2-resident across all 8 phases.
//     h writes already bypass L2 (relaxed agent-scope atomic store to LLC);
//     h reads are NT (safe: ring depth 9 > TPL 8 -> address never cached
//     stale within a launch; launch boundaries handle cross-launch).
// Barrier: RELAXED-only device atomics (no acquire/release -> no buffer_inv).
// Inner K-loop = R4-proven body, untouched.
// ---------------------------------------------------------------------------

__device__ __forceinline__ void gbar(unsigned int* cnt, unsigned int target, int thr) {
    __syncthreads();                 // drains vmcnt: all this block's h-stores at LLC
    if (thr == 0) {
        asm volatile("" ::: "memory");
        __hip_atomic_fetch_add(cnt, 1u, __ATOMIC_RELAXED, __HIP_MEMORY_SCOPE_AGENT);
        while (__hip_atomic_load(cnt, __ATOMIC_RELAXED, __HIP_MEMORY_SCOPE_AGENT) < target)
            __builtin_amdgcn_s_sleep(4);
        asm volatile("" ::: "memory");
    }
    __syncthreads();
}

__device__ __forceinline__ void run_part(
    const int thr, const int bt, const int htp,
    const int cx, const int nchunks,
    const half_t* __restrict__ xb, const int ldx,
    const half_t* __restrict__ hp,
    const half_t* __restrict__ Wih, const half_t* __restrict__ Whh,
    const float bv,
    float& cpe, float& cpo, half_t* __restrict__ hn_out,
    const float* __restrict__ fcWt,
    float& fp0, float& fp1, float& fp2,
    half_t* A_s, float* gate_s, float* h_s, float* fcw_s,
    const bool do_fc)
{
    const int wave = thr >> 6, lane = thr & 63;
    const int gate = wave >> 1, mh = wave & 1;
    const int quad = lane >> 4, l15 = lane & 15;
    const int ar = thr >> 3;             // A staging row 0..63
    const int ak = (thr & 7) * 8;        // A staging k-offset (halfs)
    const int ghW = gate * 32 + (htp >> 1);
    const int jo  = (htp & 1) * 2;       // fragment col-half select

    f4 acc0 = (f4){bv, bv, bv, bv};      // rows mh*32 + 0..15
    f4 acc1 = acc0;                      // rows mh*32 + 16..31

    // streaming A (x / h-prev): non-temporal -> never evicts W from L2
    auto loadA = [&](int ck) -> f4 {
        const half_t* Ab; int lda, k0;
        if (ck < cx) { Ab = xb; lda = ldx; k0 = ck * 64; }
        else         { Ab = hp; lda = H_;  k0 = (ck - cx) * 64; }
        return __builtin_nontemporal_load(
            (const f4*)&Ab[(size_t)(bt * 64 + ar) * lda + k0 + ak]);
    };
    // W: NORMAL cached loads -> L2-resident working set (3.1MB/XCD)
    auto fetchW = [&](int ck, h8& r0, h8& r1) {
        const half_t* Wb; int ckk, NC;
        if (ck < cx) { Wb = Wih; ckk = ck;      NC = cx; }
        else         { Wb = Whh; ckk = ck - cx; NC = 16; }
        const half_t* base = Wb + ((size_t)(((ghW * NC) + ckk) * 4 + jo) * 64 + lane) * 8;
        r0 = *(const h8*)(base + 0 * 512);
        r1 = *(const h8*)(base + 1 * 512);
    };

    // ---- prologue: window 0 A loads + W chunks 0..2 ----
    h8 W0a,W0b, W1a,W1b, W2a,W2b, W3a,W3b;
    f4 p0, p1, p2, p3;
    f4 a0_ = loadA(0), a1_ = loadA(1), a2_ = loadA(2), a3_ = loadA(3);
    p0 = loadA(4); p1 = loadA(5); p2 = loadA(6); p3 = loadA(7);
    fetchW(0, W0a, W0b);
    fetchW(1, W1a, W1b);
    fetchW(2, W2a, W2b);

    // fcW slice prefetch (l1 only): streaming const -> NT, hidden under K-loop
    float fpre = 0.f;
    if (do_fc && thr < 384)
        fpre = __builtin_nontemporal_load(
            &fcWt[(size_t)(thr >> 4) * (S_ * H_) + htp * 16 + (thr & 15)]);

    *(f4*)&A_s[0 * 4608 + ar * 72 + ak] = a0_;
    *(f4*)&A_s[1 * 4608 + ar * 72 + ak] = a1_;
    *(f4*)&A_s[2 * 4608 + ar * 72 + ak] = a2_;
    *(f4*)&A_s[3 * 4608 + ar * 72 + ak] = a3_;
    __syncthreads();   // window 0 visible

    for (int s = 0; s < nchunks; s += 4) {
        const int rem = nchunks - s;
        const int ns = rem < 4 ? rem : 4;                 // block-uniform
        int ns2 = rem - 4; if (ns2 < 0) ns2 = 0; if (ns2 > 4) ns2 = 4;
        const int bufo = ((s >> 2) & 1) * 18432;          // read buffer (halfs)
        const int obuf = 18432 - bufo;                    // write buffer

        // issue NEXT window's A loads (latency hides under compute)
        if (ns2 > 0) p0 = loadA(s + 4);
        if (ns2 > 1) p1 = loadA(s + 5);
        if (ns2 > 2) p2 = loadA(s + 6);
        if (ns2 > 3) p3 = loadA(s + 7);

        // compute ns chunks; W pipeline 3 ahead (4 sets, chunk c -> set c&3)
        #define STEP(i, C0,C1, N0,N1)                                                          \
        if (i < ns) {                                                                          \
            if (s + i + 3 < nchunks) fetchW(s + i + 3, N0, N1);                                \
            h8 a0 = *(const h8*)&A_s[bufo + i * 4608 + (mh * 32 + l15) * 72 + quad * 8];       \
            h8 a1 = *(const h8*)&A_s[bufo + i * 4608 + (mh * 32 + 16 + l15) * 72 + quad * 8];  \
            h8 a2 = *(const h8*)&A_s[bufo + i * 4608 + (mh * 32 + l15) * 72 + 32 + quad * 8];  \
            h8 a3 = *(const h8*)&A_s[bufo + i * 4608 + (mh * 32 + 16 + l15) * 72 + 32 + quad * 8]; \
            acc0 = __builtin_amdgcn_mfma_f32_16x16x32_f16(a0, C0, acc0, 0, 0, 0);              \
            acc1 = __builtin_amdgcn_mfma_f32_16x16x32_f16(a1, C0, acc1, 0, 0, 0);              \
            acc0 = __builtin_amdgcn_mfma_f32_16x16x32_f16(a2, C1, acc0, 0, 0, 0);              \
            acc1 = __builtin_amdgcn_mfma_f32_16x16x32_f16(a3, C1, acc1, 0, 0, 0);              \
        }
        STEP(0, W0a,W0b, W3a,W3b)
        STEP(1, W1a,W1b, W0a,W0b)
        STEP(2, W2a,W2b, W1a,W1b)
        STEP(3, W3a,W3b, W2a,W2b)
        #undef STEP

        // store next window into the other buffer; ONE barrier per window
        if (ns2 > 0) {
            /*always*/       *(f4*)&A_s[obuf + 0 * 4608 + ar * 72 + ak] = p0;
            if (ns2 > 1)     *(f4*)&A_s[obuf + 1 * 4608 + ar * 72 + ak] = p1;
            if (ns2 > 2)     *(f4*)&A_s[obuf + 2 * 4608 + ar * 72 + ak] = p2;
            if (ns2 > 3)     *(f4*)&A_s[obuf + 3 * 4608 + ar * 72 + ak] = p3;
            __syncthreads();
        }
    }
    __syncthreads();   // all waves done with A windows before LDS reuse

    // scatter gates (C/D layout: col=lane&15, row=quad*4+reg)
    #pragma unroll
    for (int r = 0; r < 4; ++r) {
        gate_s[gate * (64 * 17) + (mh * 32 + quad * 4 + r) * 17 + l15]      = acc0[r];
        gate_s[gate * (64 * 17) + (mh * 32 + 16 + quad * 4 + r) * 17 + l15] = acc1[r];
    }
    __syncthreads();

    // cell update: 64 rows x 16 cols; thread -> (row=thr>>3, col pair 2c,2c+1)
    // c lives in registers across phases; h written via relaxed agent-scope
    // atomic store (write-through past non-coherent XCD L2, no L2 pollution).
    {
        const int erow = thr >> 3, ecp = thr & 7;
        const int c0 = 2 * ecp;
        float ge = gate_s[0 * (64 * 17) + erow * 17 + c0];
        float go_ = gate_s[0 * (64 * 17) + erow * 17 + c0 + 1];
        float fe = gate_s[1 * (64 * 17) + erow * 17 + c0];
        float fo = gate_s[1 * (64 * 17) + erow * 17 + c0 + 1];
        float gge = gate_s[2 * (64 * 17) + erow * 17 + c0];
        float ggo = gate_s[2 * (64 * 17) + erow * 17 + c0 + 1];
        float oe = gate_s[3 * (64 * 17) + erow * 17 + c0];
        float oo = gate_s[3 * (64 * 17) + erow * 17 + c0 + 1];
        float sie = 1.f / (1.f + __expf(-ge)),  sio = 1.f / (1.f + __expf(-go_));
        float sfe = 1.f / (1.f + __expf(-fe)),  sfo = 1.f / (1.f + __expf(-fo));
        float soe = 1.f / (1.f + __expf(-oe)),  soo = 1.f / (1.f + __expf(-oo));
        float tge = tanhf(gge), tgo = tanhf(ggo);
        float cne = sfe * cpe + sie * tge;
        float cno = sfo * cpo + sio * tgo;
        cpe = cne; cpo = cno;
        float hne = soe * tanhf(cne);
        float hno = soo * tanhf(cno);
        union { half_t h[2]; unsigned int u; } cv;
        cv.h[0] = (half_t)hne; cv.h[1] = (half_t)hno;
        size_t hidx = (size_t)(bt * 64 + erow) * H_ + htp * 16 + c0;
        __hip_atomic_store((unsigned int*)&hn_out[hidx], cv.u,
                           __ATOMIC_RELAXED, __HIP_MEMORY_SCOPE_AGENT);
        if (do_fc) { h_s[erow * 17 + c0] = hne; h_s[erow * 17 + c0 + 1] = hno; }
    }

    if (do_fc) {
        if (thr < 384) fcw_s[thr] = fpre;   // [24][16] staged from prefetch
        __syncthreads();
        #pragma unroll
        for (int q = 0; q < 3; ++q) {
            int p = thr + q * 512;           // 0..1535 = 64b x 24o
            int o = p >> 6, bb = p & 63;
            float s2 = 0.f;
            #pragma unroll
            for (int j = 0; j < 16; ++j)
                s2 += h_s[bb * 17 + j] * fcw_s[o * 16 + j];
            if (q == 0) fp0 += s2; else if (q == 1) fp1 += s2; else fp2 += s2;
        }
    }
    __syncthreads();   // guard LDS reuse by the next part
}

__global__ __launch_bounds__(512, 2)
void k_mphase(int tbeg, int tcnt, unsigned int* __restrict__ cnt,
              const half_t* __restrict__ x_h,
              const half_t* __restrict__ Wih0, const half_t* __restrict__ Whh0,
              const float* __restrict__ bias0, float* __restrict__ c1g, half_t* __restrict__ h1r,
              const half_t* __restrict__ Wih1, const half_t* __restrict__ Whh1,
              const float* __restrict__ bias1, float* __restrict__ c2g, half_t* __restrict__ h2r,
              const float* __restrict__ fcW, float* __restrict__ out_part)
{
    // double-buffered A: 2 x [4][64*72] halfs = 73728 B; epilogue LDS unioned
    __shared__ __align__(16) char smraw[73728];
    half_t* A_s    = (half_t*)smraw;
    float*  gate_s = (float*)smraw;                  // [4][64*17] = 17408 B
    float*  h_s    = (float*)(smraw + 17408);        // [64*17]    =  4352 B
    float*  fcw_s  = (float*)(smraw + 21760);        // [24*16]    =  1536 B

    const int n   = blockIdx.x;
    const int htp = (n & 7) + 8 * ((n >> 3) & 7);    // htp % 8 == n % 8 (XCD-resident W)
    const int bt  = (n >> 6) & 3;
    const int thr = threadIdx.x;
    const int wave = thr >> 6, lane = thr & 63;
    const int gate = wave >> 1, l15 = lane & 15;

    // persistent per-launch state (block owns its (b,h) slice exclusively);
    // c load/store once per launch, NT (streaming, don't evict W)
    const int erow = thr >> 3, ecp = thr & 7;
    const size_t cb = (size_t)(bt * 64 + erow) * H_ + htp * 16 + 2 * ecp;
    float c1e = __builtin_nontemporal_load(&c1g[cb]);
    float c1o = __builtin_nontemporal_load(&c1g[cb + 1]);
    float c2e = __builtin_nontemporal_load(&c2g[cb]);
    float c2o = __builtin_nontemporal_load(&c2g[cb + 1]);
    float fp0 = 0.f, fp1 = 0.f, fp2 = 0.f;
    const float bv0 = bias0[gate * H_ + htp * 16 + l15];
    const float bv1 = bias1[gate * H_ + htp * 16 + l15];

    for (int p = 0; p < tcnt; ++p) {
        const int t = tbeg + p;
        if (t < S_) {       // layer-0: h1(t) from x(t), h1(t-1)
            run_part(thr, bt, htp, /*cx=*/1, /*nchunks=*/17,
                     x_h + (size_t)t * F_, S_ * F_,
                     h1r + (size_t)((t + RING_ - 1) % RING_) * B_ * H_,
                     Wih0, Whh0, bv0, c1e, c1o,
                     h1r + (size_t)(t % RING_) * B_ * H_,
                     nullptr, fp0, fp1, fp2,
                     A_s, gate_s, h_s, fcw_s, false);
        }
        if (t > 0) {        // layer-1: h2(t-1) from h1(t-1), h2(t-2); + FC
            const int tt = t - 1;
            run_part(thr, bt, htp, /*cx=*/16, /*nchunks=*/32,
                     h1r + (size_t)(tt % RING_) * B_ * H_, H_,
                     h2r + (size_t)((tt + RING_ - 1) % RING_) * B_ * H_,
                     Wih1, Whh1, bv1, c2e, c2o,
                     h2r + (size_t)(tt % RING_) * B_ * H_,
                     fcW + (size_t)tt * H_, fp0, fp1, fp2,
                     A_s, gate_s, h_s, fcw_s, true);
        }
        gbar(cnt, 256u * (unsigned)(t + 1), thr);
    }

    // write back persistent state (NT; launch boundary makes it visible)
    __builtin_nontemporal_store(c1e, &c1g[cb]);
    __builtin_nontemporal_store(c1o, &c1g[cb + 1]);
    __builtin_nontemporal_store(c2e, &c2g[cb]);
    __builtin_nontemporal_store(c2o, &c2g[cb + 1]);
    #pragma unroll
    for (int q = 0; q < 3; ++q) {
        int p = thr + q * 512;
        int o = p >> 6, bb = p & 63;
        size_t oi = (size_t)htp * (B_ * O_) + (bt * 64 + bb) * O_ + o;
        float prev = __builtin_nontemporal_load(&out_part[oi]);
        __builtin_nontemporal_store(prev + (q == 0 ? fp0 : (q == 1 ? fp1 : fp2)),
                                    &out_part[oi]);
    }
}

__global__ void k_final(const float* __restrict__ out_part, const float* __restrict__ fcb,
                        float* __restrict__ out) {
    int i = blockIdx.x * blockDim.x + threadIdx.x;
    if (i >= B_ * O_) return;
    int o = i % O_;
    float s = fcb[o];
    for (int tl = 0; tl < NT_; ++tl) s += out_part[(size_t)tl * (B_ * O_) + i];
    out[i] = s;
}

extern "C" void kernel_launch(void* const* d_in, const int* in_sizes, int n_in,
                              void* d_out, int out_size, void* d_ws, size_t ws_size,
                              hipStream_t stream) {
    const float* x    = (const float*)d_in[0];
    const float* Wih0 = (const float*)d_in[1];
    const float* Whh0 = (const float*)d_in[2];
    const float* bih0 = (const float*)d_in[3];
    const float* bhh0 = (const float*)d_in[4];
    const float* Wih1 = (const float*)d_in[5];
    const float* Whh1 = (const float*)d_in[6];
    const float* bih1 = (const float*)d_in[7];
    const float* bhh1 = (const float*)d_in[8];
    const float* fcW  = (const float*)d_in[9];
    const float* fcb  = (const float*)d_in[10];

    char* ws = (char*)d_ws;
    half_t* h1r    = (half_t*)(ws + OFF_H1);
    half_t* h2r    = (half_t*)(ws + OFF_H2);
    float*  c1     = (float*)(ws + OFF_C1);
    float*  c2     = (float*)(ws + OFF_C2);
    float*  opart  = (float*)(ws + OFF_OP);
    unsigned int* cnt = (unsigned int*)(ws + OFF_CNT);
    float*  bias0  = (float*)(ws + OFF_BIAS0);
    float*  bias1  = (float*)(ws + OFF_BIAS1);
    half_t* x_h    = (half_t*)(ws + OFF_XH);
    half_t* wih0_p = (half_t*)(ws + OFF_WIH0);
    half_t* whh0_p = (half_t*)(ws + OFF_WHH0);
    half_t* wih1_p = (half_t*)(ws + OFF_WIH1);
    half_t* whh1_p = (half_t*)(ws + OFF_WHH1);

    // zero h rings + c states + FC partials + barrier counter
    hipMemsetAsync(d_ws, 0, ZBYTES, stream);

    k_bias<<<dim3((G_ + 255) / 256), dim3(256), 0, stream>>>(bih0, bhh0, bih1, bhh1, bias0, bias1);
    k_cvt<<<dim3(2048), dim3(256), 0, stream>>>(x, x_h, B_ * S_ * F_);
    k_pack<<<dim3(128),  dim3(256), 0, stream>>>(Wih0, wih0_p, 1);
    k_pack<<<dim3(2048), dim3(256), 0, stream>>>(Whh0, whh0_p, 16);
    k_pack<<<dim3(2048), dim3(256), 0, stream>>>(Wih1, wih1_p, 16);
    k_pack<<<dim3(2048), dim3(256), 0, stream>>>(Whh1, whh1_p, 16);

    for (int tb = 0; tb <= S_; tb += TPL_) {
        int tc = S_ + 1 - tb; if (tc > TPL_) tc = TPL_;
        k_mphase<<<dim3(256), dim3(512), 0, stream>>>(tb, tc, cnt, x_h,
                                                      wih0_p, whh0_p, bias0, c1, h1r,
                                                      wih1_p, whh1_p, bias1, c2, h2r,
                                                      fcW, opart);
    }
    k_final<<<dim3((B_ * O_ + 255) / 256), dim3(256), 0, stream>>>(opart, fcb, (float*)d_out);
}